// Round 21
// baseline (993.317 us; speedup 1.0000x reference)
//
#include <hip/hip_runtime.h>

#define NN 64
#define NI 6
#define TT 1024
#define BB 1024
#define TB (TT * BB)
#define NSCALE 0.13416407864998738f        // sqrt(2/alpha) * sigma
#define ARNSCALE 0.013416407864998739f     // alpha * NSCALE
#define RREC 72                            // rnu record: 64 rn' (-> x) + 6 uterm + 2 pad(0)
#define BSTRIDE (TT * RREC)                // 73728 floats per batch

typedef __attribute__((ext_vector_type(2))) unsigned int u32x2;

__device__ __forceinline__ float rdlane(float v, int l) {
    return __int_as_float(__builtin_amdgcn_readlane(__float_as_int(v), l));
}

// DPP row_ror:J as an operand modifier: independent per instruction, no serial chain.
template<int J>
__device__ __forceinline__ float rorj(float v) {
    return __int_as_float(__builtin_amdgcn_update_dpp(
        __float_as_int(v), __float_as_int(v), 0x120 + J, 0xF, 0xF, false));
}

#if defined(__has_builtin)
# if __has_builtin(__builtin_amdgcn_permlane16_swap)
#  define HAVE_PL16 1
# endif
#endif

// ---------------- Pass 1: build rnu[b][t][72] in d_ws ----------------
__global__ __launch_bounds__(256) void build_rnu(
    const float* __restrict__ u,
    const float* __restrict__ rn,
    const float* __restrict__ inn,
    float* __restrict__ rnu)
{
    const int blk = blockIdx.x;
    const int t   = blk >> 4;
    const int b0  = (blk & 15) * 64;
    const int tid = threadIdx.x;

    __shared__ float lds[64][65];

    {   const int c  = tid & 63;
        const int r0 = tid >> 6;
#pragma unroll
        for (int it = 0; it < 16; ++it) {
            const int n = 4 * it + r0;
            lds[c][n] = ARNSCALE * rn[n * TB + t * BB + b0 + c];
        }
    }
    __syncthreads();
    {   const int cn = tid & 63;
        const int r0 = tid >> 6;
#pragma unroll
        for (int it = 0; it < 16; ++it) {
            const int r = 4 * it + r0;
            rnu[(b0 + r) * BSTRIDE + t * RREC + cn] = lds[r][cn];
        }
    }
    {   const int i  = tid & 7;
        const int br = tid >> 3;
#pragma unroll
        for (int it = 0; it < 2; ++it) {
            const int b = br + 32 * it;
            float v = 0.0f;
            if (i < NI) {
                const int g = i * TB + t * BB + b0 + b;
                v = fmaf(NSCALE, inn[g], u[g]);
            }
            rnu[(b0 + b) * BSTRIDE + t * RREC + 64 + i] = v;
        }
    }
}

// ---------------- Pass 2: recurrence, pure-VALU DPP broadcast ----------------
// 1024 blocks x 64 thr (4 waves/CU). lane = neuron, block = batch. NO LDS in the
// step: 3 parallel half-wave swaps give lanes x[n], x[n^16], x[n^32], x[n^48];
// the within-16 offsets come from independent v_mov_dpp row_ror:j (static operand
// modifier -> no serial rotate chain, r11's mistake). Weights pre-gathered in
// rotated (j,g) order; row_ror direction resolved by a one-time lane-id probe.
__global__ __launch_bounds__(64, 1) void latent_rnn_dppb(
    const float* __restrict__ rn_in,  // (B, T, 72) — reads
    float* __restrict__ x_out,        // (B, T, 72) — x writeback (same buffer)
    const float* __restrict__ Winp,   // (64, 6)
    const float* __restrict__ Wrec)   // (64, 64)
{
    const int hw = blockIdx.x;
    const int b  = (hw & 7) * 128 + (hw >> 3);   // XCD swizzle: 128 batches/XCD
    const int n  = threadIdx.x;

    // ---- probe row_ror direction: lane 0 sees source lane id (1 or 15) ----
    int d;
    {
        int pr = __builtin_amdgcn_update_dpp(n, n, 0x121, 0xF, 0xF, false); // row_ror:1
        d = __builtin_amdgcn_readfirstlane(pr) & 15;   // d in {1, 15}; 15 == -1 mod 16
    }

    // ---- probe permlane32_swap component convention ----
    bool useX32;
    {
        u32x2 pb = __builtin_amdgcn_permlane32_swap((unsigned)n, (unsigned)n, false, false);
        useX32 = (pb.x == (unsigned)(n ^ 32));
    }
#ifdef HAVE_PL16
    bool useX16;
    {
        u32x2 pb = __builtin_amdgcn_permlane16_swap((unsigned)n, (unsigned)n, false, false);
        useX16 = (pb.x == (unsigned)(n ^ 16));
    }
#endif

    // ---- rotated weight gather: wr[g][j] = W[n][ ((n&48)|((n+d*j)&15)) ^ (16g) ]
    float wr0[16], wr1[16], wr2[16], wr3[16];
#pragma unroll
    for (int j = 0; j < 16; ++j) {
        const int k15 = (n + d * j) & 15;
        const int kb  = (n & 48) | k15;
        wr0[j] = Wrec[n * NN + (kb ^  0)];
        wr1[j] = Wrec[n * NN + (kb ^ 16)];
        wr2[j] = Wrec[n * NN + (kb ^ 32)];
        wr3[j] = Wrec[n * NN + (kb ^ 48)];
    }
    float wi[NI];
#pragma unroll
    for (int i = 0; i < NI; ++i) wi[i] = Winp[n * NI + i];
#pragma unroll
    for (int j = 0; j < 16; ++j) {
        asm volatile("" : "+v"(wr0[j])); asm volatile("" : "+v"(wr1[j]));
        asm volatile("" : "+v"(wr2[j])); asm volatile("" : "+v"(wr3[j]));
    }

    const float* rptr = rn_in + b * BSTRIDE + n;             // rn' lane view
    const float* uptr = rn_in + b * BSTRIDE + 64 + (n & 7);  // uterm lane view
    float*       xdst = x_out + b * BSTRIDE + n;             // x writeback view

    // prefetch rings (depth 4, static slots): rnb/utb hold step t's rn'/uterm
    float rnb[4], utb[4];
#pragma unroll
    for (int dd = 0; dd < 4; ++dd) {
        rnb[dd] = rptr[dd * RREC];
        utb[dd] = uptr[dd * RREC];
    }

    float xreg = 0.0f;

#define ROW(J)                                                                \
    do {                                                                      \
        const float y0 = rorj<J>(xg0);                                        \
        const float y1 = rorj<J>(xg1);                                        \
        const float y2 = rorj<J>(xg2);                                        \
        const float y3 = rorj<J>(xg3);                                        \
        p[(4*(J) + 0) & 7] = fmaf(y0, wr0[J], p[(4*(J) + 0) & 7]);            \
        p[(4*(J) + 1) & 7] = fmaf(y1, wr1[J], p[(4*(J) + 1) & 7]);            \
        p[(4*(J) + 2) & 7] = fmaf(y2, wr2[J], p[(4*(J) + 2) & 7]);            \
        p[(4*(J) + 3) & 7] = fmaf(y3, wr3[J], p[(4*(J) + 3) & 7]);            \
    } while (0)

#define STEP_BODY(tcur, slot, TPEXPR)                                         \
    do {                                                                      \
        const float rcur = rnb[slot];                                         \
        const float ucur = utb[slot];                                         \
        { const int tp = (TPEXPR);                                            \
          rnb[slot] = rptr[tp * RREC];                                        \
          utb[slot] = uptr[tp * RREC]; }                                      \
        /* half-wave swaps: xg0=x[n], xg1=x[n^16], xg2=x[n^32], xg3=x[n^48] */\
        const float xg0 = xreg;                                               \
        float xg2, xg1, xg3;                                                  \
        {                                                                     \
            u32x2 s = __builtin_amdgcn_permlane32_swap(                       \
                __float_as_uint(xg0), __float_as_uint(xg0), false, false);    \
            xg2 = __uint_as_float(useX32 ? s.x : s.y);                        \
        }                                                                     \
        SWAP16(xg1, xg0);                                                     \
        SWAP16(xg3, xg2);                                                     \
        /* uterm products seed 6 of the 8 accumulators */                     \
        float p[8];                                                           \
        p[0] = rdlane(ucur, 0) * wi[0];                                       \
        p[1] = rdlane(ucur, 1) * wi[1];                                       \
        p[2] = rdlane(ucur, 2) * wi[2];                                       \
        p[3] = rdlane(ucur, 3) * wi[3];                                       \
        p[4] = rdlane(ucur, 4) * wi[4];                                       \
        p[5] = rdlane(ucur, 5) * wi[5];                                       \
        p[6] = 0.0f; p[7] = 0.0f;                                             \
        /* j = 0: direct operands */                                          \
        p[0] = fmaf(xg0, wr0[0], p[0]);                                       \
        p[1] = fmaf(xg1, wr1[0], p[1]);                                       \
        p[2] = fmaf(xg2, wr2[0], p[2]);                                       \
        p[3] = fmaf(xg3, wr3[0], p[3]);                                       \
        ROW(1);  ROW(2);  ROW(3);  ROW(4);  ROW(5);                           \
        ROW(6);  ROW(7);  ROW(8);  ROW(9);  ROW(10);                          \
        ROW(11); ROW(12); ROW(13); ROW(14); ROW(15);                          \
        const float pre = ((p[0] + p[1]) + (p[2] + p[3])) +                   \
                          ((p[4] + p[5]) + (p[6] + p[7]));                    \
        const float xn  = fmaf(0.9f, xreg,                                    \
                               fmaf(0.1f, fmaxf(pre, 0.f), rcur));            \
        xreg = xn;                                                            \
        xdst[(tcur) * RREC] = xn;             /* record[t] <- x[t+1] */       \
    } while (0)

#ifdef HAVE_PL16
#define SWAP16(dst, src)                                                      \
    {                                                                         \
        u32x2 s = __builtin_amdgcn_permlane16_swap(                           \
            __float_as_uint(src), __float_as_uint(src), false, false);        \
        dst = __uint_as_float(useX16 ? s.x : s.y);                            \
    }
#else
#define SWAP16(dst, src) dst = __shfl_xor((src), 16);
#endif

#define STEP_NC(tcur, slot) STEP_BODY(tcur, slot, (tcur) + 4)
#define STEP_CL(tcur, slot) \
    STEP_BODY(tcur, slot, ((tcur) + 4 < TT - 1) ? (tcur) + 4 : TT - 1)

#pragma unroll 1
    for (int t = 0; t < 1020; t += 4) {
        STEP_NC(t + 0, 0);
        STEP_NC(t + 1, 1);
        STEP_NC(t + 2, 2);
        STEP_NC(t + 3, 3);
    }
    STEP_CL(1020, 0);
    STEP_CL(1021, 1);
    STEP_CL(1022, 2);
#undef STEP_NC
#undef STEP_CL
#undef STEP_BODY
#undef SWAP16
#undef ROW
}

// ---------------- Pass 3: transpose + fused output projection ----------------
__global__ __launch_bounds__(256) void trans_out(
    const float* __restrict__ rnu,
    const float* __restrict__ Wout,     // (2, 64)
    float* __restrict__ states,         // (64, T, B)
    float* __restrict__ outputs)        // (2, T, B)
{
    const int blk = blockIdx.x;
    const int t   = blk >> 4;
    const int b0  = (blk & 15) * 64;
    const int tid = threadIdx.x;

    __shared__ float xt[64][65];   // [b][n]
    __shared__ float wo[2][64];

    if (tid < 128) wo[tid >> 6][tid & 63] = Wout[tid];

    const int col = tid & 63;
    const int r0  = tid >> 6;
    if (t == 0) {
#pragma unroll
        for (int it = 0; it < 16; ++it) xt[4 * it + r0][col] = 0.0f;
    } else {
#pragma unroll
        for (int it = 0; it < 16; ++it) {
            const int r = 4 * it + r0;
            xt[r][col] = rnu[(b0 + r) * BSTRIDE + (t - 1) * RREC + col];
        }
    }
    __syncthreads();

#pragma unroll
    for (int it = 0; it < 16; ++it) {
        const int n = 4 * it + r0;
        states[n * TB + t * BB + b0 + col] = xt[col][n];
    }

    if (tid < 128) {
        const int o  = tid >> 6;
        const int bb = tid & 63;
        float acc = 0.0f;
#pragma unroll
        for (int k = 0; k < NN; ++k) acc = fmaf(xt[bb][k], wo[o][k], acc);
        outputs[o * TB + t * BB + b0 + bb] = acc;
    }
}

// ---------------- Fallback (no-workspace path, proven correct) ----------------
#define BARRIER() do {                                                        \
    __builtin_amdgcn_sched_barrier(0);                                        \
    asm volatile("s_waitcnt lgkmcnt(0)\n\ts_barrier" ::: "memory");           \
    __builtin_amdgcn_sched_barrier(0);                                        \
} while (0)

__global__ __launch_bounds__(256, 1) void latent_rnn_fb(
    const float* __restrict__ u, const float* __restrict__ rn,
    const float* __restrict__ inn, const float* __restrict__ Winp,
    const float* __restrict__ Wrec, float* __restrict__ states)
{
    const int hw  = blockIdx.x;
    const int lb  = (hw & 7) * 32 + (hw >> 3);
    const int b0  = lb * 4;
    const int tid = threadIdx.x;
    const int l   = tid & 63;
    const int w   = tid >> 6;
    const int n   = tid >> 2;
    const int bs  = tid & 3;

    __shared__ float rnT[2][NN][5];
    __shared__ float xT[2][NN][5];
    __shared__ float iT[2][4][8];

    float wreg[NN];
#pragma unroll
    for (int k = 0; k < NN; k += 4) {
        const float4 w4 = *reinterpret_cast<const float4*>(Wrec + l * NN + k);
        wreg[k] = w4.x; wreg[k+1] = w4.y; wreg[k+2] = w4.z; wreg[k+3] = w4.w;
    }
    float wi[NI];
#pragma unroll
    for (int i = 0; i < NI; ++i) wi[i] = Winp[l * NI + i];

    const float* rsrc = rn + n * TB + b0 + bs;
    float*       sdst = states + n * TB + b0 + bs;
    const bool  ist  = (tid < NI * 4);
    const int   ii   = tid >> 2;
    const int   ib   = tid & 3;
    const float* usrc = u   + ii * TB + b0 + ib;
    const float* isrc = inn + ii * TB + b0 + ib;

    rnT[0][n][bs] = rsrc[0];
    if (ist) iT[0][ib][ii] = fmaf(NSCALE, isrc[0], usrc[0]);
    xT[0][l][w] = 0.0f;

    float rnPF[4], uPF[4], iPF[4];
#pragma unroll
    for (int dd = 0; dd < 4; ++dd) {
        rnPF[dd] = rsrc[(dd + 1) * BB];
        if (ist) { uPF[dd] = usrc[(dd + 1) * BB]; iPF[dd] = isrc[(dd + 1) * BB]; }
    }
    __syncthreads();

    float xreg = 0.0f;

#define FSTEP(tcur, slot, CC)                                                 \
  {                                                                           \
    sdst[(tcur) * BB] = xT[CC][n][bs];                                        \
    const float rcur = rnT[CC][l][w];                                         \
    const float4 iv0 = *reinterpret_cast<const float4*>(&iT[CC][w][0]);       \
    const float2 iv1 = *reinterpret_cast<const float2*>(&iT[CC][w][4]);       \
    float a0 = 0.f, a1 = 0.f, a2 = 0.f, a3 = 0.f;                             \
    _Pragma("unroll")                                                         \
    for (int k = 0; k < NN; k += 4) {                                         \
        a0 = fmaf(rdlane(xreg, k + 0), wreg[k + 0], a0);                      \
        a1 = fmaf(rdlane(xreg, k + 1), wreg[k + 1], a1);                      \
        a2 = fmaf(rdlane(xreg, k + 2), wreg[k + 2], a2);                      \
        a3 = fmaf(rdlane(xreg, k + 3), wreg[k + 3], a3);                      \
    }                                                                         \
    a0 = fmaf(iv0.x, wi[0], a0); a1 = fmaf(iv0.y, wi[1], a1);                 \
    a2 = fmaf(iv0.z, wi[2], a2); a3 = fmaf(iv0.w, wi[3], a3);                 \
    a0 = fmaf(iv1.x, wi[4], a0); a1 = fmaf(iv1.y, wi[5], a1);                 \
    const float pre = (a0 + a1) + (a2 + a3);                                  \
    const float xn  = fmaf(0.9f, xreg,                                        \
                           fmaf(0.1f, fmaxf(pre, 0.f), ARNSCALE * rcur));     \
    xreg = xn;                                                                \
    xT[(CC) ^ 1][l][w] = xn;                                                  \
    rnT[(CC) ^ 1][n][bs] = rnPF[slot];                                        \
    if (ist) iT[(CC) ^ 1][ib][ii] = fmaf(NSCALE, iPF[slot], uPF[slot]);       \
    { int tp = (tcur) + 5; if (tp > TT - 2) tp = TT - 2;                      \
      rnPF[slot] = rsrc[tp * BB];                                             \
      if (ist) { uPF[slot] = usrc[tp * BB]; iPF[slot] = isrc[tp * BB]; } }    \
    BARRIER();                                                                \
  }

#pragma unroll 1
    for (int t = 0; t < 1020; t += 4) {
        FSTEP(t + 0, 0, 0);
        FSTEP(t + 1, 1, 1);
        FSTEP(t + 2, 2, 0);
        FSTEP(t + 3, 3, 1);
    }
    FSTEP(1020, 0, 0);
    FSTEP(1021, 1, 1);
    FSTEP(1022, 2, 0);
#undef FSTEP

    sdst[(TT - 1) * BB] = xT[1][n][bs];
}

__global__ __launch_bounds__(256) void out_proj(
    const float* __restrict__ states,
    const float* __restrict__ Wout,
    float* __restrict__ outputs)
{
    const int g4 = (blockIdx.x * 256 + threadIdx.x) * 4;
    float4 a0 = {0.f, 0.f, 0.f, 0.f};
    float4 a1 = {0.f, 0.f, 0.f, 0.f};
#pragma unroll
    for (int k = 0; k < NN; ++k) {
        const float4 s = *reinterpret_cast<const float4*>(states + k * TB + g4);
        const float w0 = Wout[k];
        const float w1 = Wout[NN + k];
        a0.x = fmaf(s.x, w0, a0.x); a0.y = fmaf(s.y, w0, a0.y);
        a0.z = fmaf(s.z, w0, a0.z); a0.w = fmaf(s.w, w0, a0.w);
        a1.x = fmaf(s.x, w1, a1.x); a1.y = fmaf(s.y, w1, a1.y);
        a1.z = fmaf(s.z, w1, a1.z); a1.w = fmaf(s.w, w1, a1.w);
    }
    *reinterpret_cast<float4*>(outputs + g4)      = a0;
    *reinterpret_cast<float4*>(outputs + TB + g4) = a1;
}

extern "C" void kernel_launch(void* const* d_in, const int* in_sizes, int n_in,
                              void* d_out, int out_size, void* d_ws, size_t ws_size,
                              hipStream_t stream) {
    const float* u    = (const float*)d_in[0];
    const float* rn   = (const float*)d_in[1];
    const float* inn  = (const float*)d_in[2];
    const float* Winp = (const float*)d_in[3];
    const float* Wrec = (const float*)d_in[4];
    const float* Wout = (const float*)d_in[5];

    float* states  = (float*)d_out;                          // 64*1024*1024
    float* outputs = (float*)d_out + (size_t)NN * TT * BB;   // 2*1024*1024

    const size_t need = (size_t)BB * TT * RREC * sizeof(float);  // ~302 MB
    if (ws_size >= need) {
        float* rnu = (float*)d_ws;
        build_rnu<<<TT * 16, 256, 0, stream>>>(u, rn, inn, rnu);
        latent_rnn_dppb<<<1024, 64, 0, stream>>>(rnu, rnu, Winp, Wrec);
        trans_out<<<TT * 16, 256, 0, stream>>>(rnu, Wout, states, outputs);
    } else {
        latent_rnn_fb<<<256, 256, 0, stream>>>(u, rn, inn, Winp, Wrec, states);
        out_proj<<<1024, 256, 0, stream>>>(states, Wout, outputs);
    }
}

// Round 22
// 746.386 us; speedup vs baseline: 1.3308x; 1.3308x over previous
//
#include <hip/hip_runtime.h>

#define NN 64
#define NI 6
#define TT 1024
#define BB 1024
#define TB (TT * BB)
#define NSCALE 0.13416407864998738f        // sqrt(2/alpha) * sigma
#define ARNSCALE 0.013416407864998739f     // alpha * NSCALE
#define RREC 72                            // rnu record: 64 rn' (-> x) + 6 uterm + 2 pad(0)
#define BSTRIDE (TT * RREC)                // 73728 floats per batch

typedef __attribute__((ext_vector_type(2))) unsigned int u32x2;

__device__ __forceinline__ float rdlane(float v, int l) {
    return __int_as_float(__builtin_amdgcn_readlane(__float_as_int(v), l));
}

// ---------------- Pass 1: build rnu[b][t][72] in d_ws ----------------
// record[0..63]  = ARNSCALE * rn[n][t][b]   (transposed, n contiguous)
// record[64..69] = u[i][t][b] + NSCALE*inn[i][t][b];  [70..71] = 0
__global__ __launch_bounds__(256) void build_rnu(
    const float* __restrict__ u,
    const float* __restrict__ rn,
    const float* __restrict__ inn,
    float* __restrict__ rnu)
{
    const int blk = blockIdx.x;
    const int t   = blk >> 4;
    const int b0  = (blk & 15) * 64;
    const int tid = threadIdx.x;

    __shared__ float lds[64][65];

    {   const int c  = tid & 63;
        const int r0 = tid >> 6;
#pragma unroll
        for (int it = 0; it < 16; ++it) {
            const int n = 4 * it + r0;
            lds[c][n] = ARNSCALE * rn[n * TB + t * BB + b0 + c];
        }
    }
    __syncthreads();
    {   const int cn = tid & 63;
        const int r0 = tid >> 6;
#pragma unroll
        for (int it = 0; it < 16; ++it) {
            const int r = 4 * it + r0;
            rnu[(b0 + r) * BSTRIDE + t * RREC + cn] = lds[r][cn];
        }
    }
    {   const int i  = tid & 7;
        const int br = tid >> 3;
#pragma unroll
        for (int it = 0; it < 2; ++it) {
            const int b = br + 32 * it;
            float v = 0.0f;
            if (i < NI) {
                const int g = i * TB + t * BB + b0 + b;
                v = fmaf(NSCALE, inn[g], u[g]);
            }
            rnu[(b0 + b) * BSTRIDE + t * RREC + 64 + i] = v;
        }
    }
}

// ---------------- Pass 2: recurrence, 2 interleaved chains per wave ----------------
// 512 blocks x 64 thr (2 waves/CU). Wave = 2 batches; lane = neuron. Each batch
// uses the r19 step (half-split LDS read: 8 ds_read_b128; permlane32 exchange;
// readlane uterm; pinned shared weights). The two chains are independent, so
// batch B's issue stream fills batch A's LDS-round-trip + dot-chain stalls
// (r19's wall: 887 cyc/step with only ~240 cyc issue -> single-chain latency).
__global__ __launch_bounds__(64, 1) void latent_rnn_2x(
    const float* __restrict__ rn_in,  // (B, T, 72) — reads
    float* __restrict__ x_out,        // (B, T, 72) — x writeback (same buffer)
    const float* __restrict__ Winp,   // (64, 6)
    const float* __restrict__ Wrec)   // (64, 64)
{
    const int hw = blockIdx.x;                   // 512 blocks
    const int g  = (hw & 7) * 64 + (hw >> 3);    // XCD swizzle: 128 batches/XCD
    const int bA = 2 * g;
    const int bB = 2 * g + 1;
    const int n  = threadIdx.x;
    const int h  = n >> 5;                       // half of x this lane reads
    const int hb = 32 * h;
    const int np = n ^ 32;

    __shared__ __align__(16) float xs[2][2][64]; // [batch][parity][x]

    // ---- permuted weight distribution (r17 scheme; shared across both batches) ----
    float ws[32], wp[32];
#pragma unroll
    for (int j = 0; j < 32; j += 4) {
        const float4 a = *reinterpret_cast<const float4*>(Wrec + n  * NN + hb + j);
        const float4 c = *reinterpret_cast<const float4*>(Wrec + np * NN + hb + j);
        ws[j] = a.x; ws[j+1] = a.y; ws[j+2] = a.z; ws[j+3] = a.w;
        wp[j] = c.x; wp[j+1] = c.y; wp[j+2] = c.z; wp[j+3] = c.w;
    }
    float wi[NI];
#pragma unroll
    for (int i = 0; i < NI; ++i) wi[i] = Winp[n * NI + i];
#pragma unroll
    for (int k = 0; k < 32; ++k) { asm volatile("" : "+v"(ws[k])); asm volatile("" : "+v"(wp[k])); }

    // ---- probe permlane32_swap component convention ----
    bool useX;
    {
        u32x2 pb = __builtin_amdgcn_permlane32_swap((unsigned)n, (unsigned)n, false, false);
        useX = (pb.x == (unsigned)np);
    }

    const float* rptrA = rn_in + bA * BSTRIDE + n;
    const float* uptrA = rn_in + bA * BSTRIDE + 64 + (n & 7);
    float*       xdstA = x_out + bA * BSTRIDE + n;
    const float* rptrB = rn_in + bB * BSTRIDE + n;
    const float* uptrB = rn_in + bB * BSTRIDE + 64 + (n & 7);
    float*       xdstB = x_out + bB * BSTRIDE + n;

    // ---- init parity 0: x[0] = 0 for both batches ----
    xs[0][0][n] = 0.0f;
    xs[1][0][n] = 0.0f;

    // prefetch rings (depth 4, static slots) per batch
    float rnbA[4], utbA[4], rnbB[4], utbB[4];
#pragma unroll
    for (int d = 0; d < 4; ++d) {
        rnbA[d] = rptrA[d * RREC];
        utbA[d] = uptrA[d * RREC];
        rnbB[d] = rptrB[d * RREC];
        utbB[d] = uptrB[d * RREC];
    }

    float xregA = 0.0f, xregB = 0.0f;

// one batch's step; unique local names via suffix S
#define CHAIN(S, XS, RNB, UTB, RPTR, UPTR, XDST, XREG, P, TP)                 \
        const float rcur##S = RNB[slot];                                      \
        const float ucur##S = UTB[slot];                                      \
        RNB[slot] = RPTR[(TP) * RREC];                                        \
        UTB[slot] = UPTR[(TP) * RREC];                                        \
        float a0##S = rdlane(ucur##S, 0) * wi[0];                             \
        float a1##S = rdlane(ucur##S, 1) * wi[1];                             \
        a0##S = fmaf(rdlane(ucur##S, 2), wi[2], a0##S);                       \
        a1##S = fmaf(rdlane(ucur##S, 3), wi[3], a1##S);                       \
        a0##S = fmaf(rdlane(ucur##S, 4), wi[4], a0##S);                       \
        a1##S = fmaf(rdlane(ucur##S, 5), wi[5], a1##S);                       \
        const float4* xrow##S = reinterpret_cast<const float4*>(&XS[P][hb]);  \
        float c0##S = 0.f, c1##S = 0.f;                                       \
        _Pragma("unroll")                                                     \
        for (int q = 0; q < 8; ++q) {                                         \
            const float4 v = xrow##S[q];                                      \
            a0##S = fmaf(v.x, ws[4*q+0], a0##S);                              \
            c0##S = fmaf(v.x, wp[4*q+0], c0##S);                              \
            a1##S = fmaf(v.y, ws[4*q+1], a1##S);                              \
            c1##S = fmaf(v.y, wp[4*q+1], c1##S);                              \
            a0##S = fmaf(v.z, ws[4*q+2], a0##S);                              \
            c0##S = fmaf(v.z, wp[4*q+2], c0##S);                              \
            a1##S = fmaf(v.w, ws[4*q+3], a1##S);                              \
            c1##S = fmaf(v.w, wp[4*q+3], c1##S);                              \
        }                                                                     \
        const float p2##S = c0##S + c1##S;                                    \
        u32x2 sw##S = __builtin_amdgcn_permlane32_swap(                       \
            __float_as_uint(p2##S), __float_as_uint(p2##S), false, false);    \
        const float pr##S = __uint_as_float(useX ? sw##S.x : sw##S.y);        \
        const float pre##S = (a0##S + a1##S) + pr##S;                         \
        const float xn##S = fmaf(0.9f, XREG,                                  \
                                 fmaf(0.1f, fmaxf(pre##S, 0.f), rcur##S));    \
        XREG = xn##S;                                                         \
        XS[(P) ^ 1][n] = xn##S;                                               \
        XDST[(tcur) * RREC] = xn##S;

#define STEP_BODY(TCUR, SLOT, P, TPEXPR)                                      \
    do {                                                                      \
        const int tcur = (TCUR);                                              \
        const int slot = (SLOT);                                              \
        const int tp   = (TPEXPR);                                            \
        CHAIN(A, xs[0], rnbA, utbA, rptrA, uptrA, xdstA, xregA, P, tp)        \
        CHAIN(B, xs[1], rnbB, utbB, rptrB, uptrB, xdstB, xregB, P, tp)        \
    } while (0)

#define STEP_NC(tcur, slot, P) STEP_BODY(tcur, slot, P, (tcur) + 4)
#define STEP_CL(tcur, slot, P) \
    STEP_BODY(tcur, slot, P, ((tcur) + 4 < TT - 1) ? (tcur) + 4 : TT - 1)

#pragma unroll 1
    for (int t = 0; t < 1020; t += 4) {
        STEP_NC(t + 0, 0, 0);
        STEP_NC(t + 1, 1, 1);
        STEP_NC(t + 2, 2, 0);
        STEP_NC(t + 3, 3, 1);
    }
    STEP_CL(1020, 0, 0);
    STEP_CL(1021, 1, 1);
    STEP_CL(1022, 2, 0);
#undef STEP_NC
#undef STEP_CL
#undef STEP_BODY
#undef CHAIN
}

// ---------------- Pass 3: transpose + fused output projection ----------------
// states[n][t][b] = (t==0) ? 0 : rnu[b][t-1][n];  outputs = states @ Wout^T.
__global__ __launch_bounds__(256) void trans_out(
    const float* __restrict__ rnu,
    const float* __restrict__ Wout,     // (2, 64)
    float* __restrict__ states,         // (64, T, B)
    float* __restrict__ outputs)        // (2, T, B)
{
    const int blk = blockIdx.x;
    const int t   = blk >> 4;
    const int b0  = (blk & 15) * 64;
    const int tid = threadIdx.x;

    __shared__ float xt[64][65];   // [b][n]
    __shared__ float wo[2][64];

    if (tid < 128) wo[tid >> 6][tid & 63] = Wout[tid];

    const int col = tid & 63;
    const int r0  = tid >> 6;
    if (t == 0) {
#pragma unroll
        for (int it = 0; it < 16; ++it) xt[4 * it + r0][col] = 0.0f;
    } else {
#pragma unroll
        for (int it = 0; it < 16; ++it) {
            const int r = 4 * it + r0;
            xt[r][col] = rnu[(b0 + r) * BSTRIDE + (t - 1) * RREC + col];
        }
    }
    __syncthreads();

#pragma unroll
    for (int it = 0; it < 16; ++it) {
        const int n = 4 * it + r0;
        states[n * TB + t * BB + b0 + col] = xt[col][n];
    }

    if (tid < 128) {
        const int o  = tid >> 6;
        const int bb = tid & 63;
        float acc = 0.0f;
#pragma unroll
        for (int k = 0; k < NN; ++k) acc = fmaf(xt[bb][k], wo[o][k], acc);
        outputs[o * TB + t * BB + b0 + bb] = acc;
    }
}

// ---------------- Fallback (no-workspace path, proven correct) ----------------
#define BARRIER() do {                                                        \
    __builtin_amdgcn_sched_barrier(0);                                        \
    asm volatile("s_waitcnt lgkmcnt(0)\n\ts_barrier" ::: "memory");           \
    __builtin_amdgcn_sched_barrier(0);                                        \
} while (0)

__global__ __launch_bounds__(256, 1) void latent_rnn_fb(
    const float* __restrict__ u, const float* __restrict__ rn,
    const float* __restrict__ inn, const float* __restrict__ Winp,
    const float* __restrict__ Wrec, float* __restrict__ states)
{
    const int hw  = blockIdx.x;
    const int lb  = (hw & 7) * 32 + (hw >> 3);
    const int b0  = lb * 4;
    const int tid = threadIdx.x;
    const int l   = tid & 63;
    const int w   = tid >> 6;
    const int n   = tid >> 2;
    const int bs  = tid & 3;

    __shared__ float rnT[2][NN][5];
    __shared__ float xT[2][NN][5];
    __shared__ float iT[2][4][8];

    float wreg[NN];
#pragma unroll
    for (int k = 0; k < NN; k += 4) {
        const float4 w4 = *reinterpret_cast<const float4*>(Wrec + l * NN + k);
        wreg[k] = w4.x; wreg[k+1] = w4.y; wreg[k+2] = w4.z; wreg[k+3] = w4.w;
    }
    float wi[NI];
#pragma unroll
    for (int i = 0; i < NI; ++i) wi[i] = Winp[l * NI + i];

    const float* rsrc = rn + n * TB + b0 + bs;
    float*       sdst = states + n * TB + b0 + bs;
    const bool  ist  = (tid < NI * 4);
    const int   ii   = tid >> 2;
    const int   ib   = tid & 3;
    const float* usrc = u   + ii * TB + b0 + ib;
    const float* isrc = inn + ii * TB + b0 + ib;

    rnT[0][n][bs] = rsrc[0];
    if (ist) iT[0][ib][ii] = fmaf(NSCALE, isrc[0], usrc[0]);
    xT[0][l][w] = 0.0f;

    float rnPF[4], uPF[4], iPF[4];
#pragma unroll
    for (int dd = 0; dd < 4; ++dd) {
        rnPF[dd] = rsrc[(dd + 1) * BB];
        if (ist) { uPF[dd] = usrc[(dd + 1) * BB]; iPF[dd] = isrc[(dd + 1) * BB]; }
    }
    __syncthreads();

    float xreg = 0.0f;

#define FSTEP(tcur, slot, CC)                                                 \
  {                                                                           \
    sdst[(tcur) * BB] = xT[CC][n][bs];                                        \
    const float rcur = rnT[CC][l][w];                                         \
    const float4 iv0 = *reinterpret_cast<const float4*>(&iT[CC][w][0]);       \
    const float2 iv1 = *reinterpret_cast<const float2*>(&iT[CC][w][4]);       \
    float a0 = 0.f, a1 = 0.f, a2 = 0.f, a3 = 0.f;                             \
    _Pragma("unroll")                                                         \
    for (int k = 0; k < NN; k += 4) {                                         \
        a0 = fmaf(rdlane(xreg, k + 0), wreg[k + 0], a0);                      \
        a1 = fmaf(rdlane(xreg, k + 1), wreg[k + 1], a1);                      \
        a2 = fmaf(rdlane(xreg, k + 2), wreg[k + 2], a2);                      \
        a3 = fmaf(rdlane(xreg, k + 3), wreg[k + 3], a3);                      \
    }                                                                         \
    a0 = fmaf(iv0.x, wi[0], a0); a1 = fmaf(iv0.y, wi[1], a1);                 \
    a2 = fmaf(iv0.z, wi[2], a2); a3 = fmaf(iv0.w, wi[3], a3);                 \
    a0 = fmaf(iv1.x, wi[4], a0); a1 = fmaf(iv1.y, wi[5], a1);                 \
    const float pre = (a0 + a1) + (a2 + a3);                                  \
    const float xn  = fmaf(0.9f, xreg,                                        \
                           fmaf(0.1f, fmaxf(pre, 0.f), ARNSCALE * rcur));     \
    xreg = xn;                                                                \
    xT[(CC) ^ 1][l][w] = xn;                                                  \
    rnT[(CC) ^ 1][n][bs] = rnPF[slot];                                        \
    if (ist) iT[(CC) ^ 1][ib][ii] = fmaf(NSCALE, iPF[slot], uPF[slot]);       \
    { int tp = (tcur) + 5; if (tp > TT - 2) tp = TT - 2;                      \
      rnPF[slot] = rsrc[tp * BB];                                             \
      if (ist) { uPF[slot] = usrc[tp * BB]; iPF[slot] = isrc[tp * BB]; } }    \
    BARRIER();                                                                \
  }

#pragma unroll 1
    for (int t = 0; t < 1020; t += 4) {
        FSTEP(t + 0, 0, 0);
        FSTEP(t + 1, 1, 1);
        FSTEP(t + 2, 2, 0);
        FSTEP(t + 3, 3, 1);
    }
    FSTEP(1020, 0, 0);
    FSTEP(1021, 1, 1);
    FSTEP(1022, 2, 0);
#undef FSTEP

    sdst[(TT - 1) * BB] = xT[1][n][bs];
}

__global__ __launch_bounds__(256) void out_proj(
    const float* __restrict__ states,
    const float* __restrict__ Wout,
    float* __restrict__ outputs)
{
    const int g4 = (blockIdx.x * 256 + threadIdx.x) * 4;
    float4 a0 = {0.f, 0.f, 0.f, 0.f};
    float4 a1 = {0.f, 0.f, 0.f, 0.f};
#pragma unroll
    for (int k = 0; k < NN; ++k) {
        const float4 s = *reinterpret_cast<const float4*>(states + k * TB + g4);
        const float w0 = Wout[k];
        const float w1 = Wout[NN + k];
        a0.x = fmaf(s.x, w0, a0.x); a0.y = fmaf(s.y, w0, a0.y);
        a0.z = fmaf(s.z, w0, a0.z); a0.w = fmaf(s.w, w0, a0.w);
        a1.x = fmaf(s.x, w1, a1.x); a1.y = fmaf(s.y, w1, a1.y);
        a1.z = fmaf(s.z, w1, a1.z); a1.w = fmaf(s.w, w1, a1.w);
    }
    *reinterpret_cast<float4*>(outputs + g4)      = a0;
    *reinterpret_cast<float4*>(outputs + TB + g4) = a1;
}

extern "C" void kernel_launch(void* const* d_in, const int* in_sizes, int n_in,
                              void* d_out, int out_size, void* d_ws, size_t ws_size,
                              hipStream_t stream) {
    const float* u    = (const float*)d_in[0];
    const float* rn   = (const float*)d_in[1];
    const float* inn  = (const float*)d_in[2];
    const float* Winp = (const float*)d_in[3];
    const float* Wrec = (const float*)d_in[4];
    const float* Wout = (const float*)d_in[5];

    float* states  = (float*)d_out;                          // 64*1024*1024
    float* outputs = (float*)d_out + (size_t)NN * TT * BB;   // 2*1024*1024

    const size_t need = (size_t)BB * TT * RREC * sizeof(float);  // ~302 MB
    if (ws_size >= need) {
        float* rnu = (float*)d_ws;
        build_rnu<<<TT * 16, 256, 0, stream>>>(u, rn, inn, rnu);
        latent_rnn_2x<<<512, 64, 0, stream>>>(rnu, rnu, Winp, Wrec);
        trans_out<<<TT * 16, 256, 0, stream>>>(rnu, Wout, states, outputs);
    } else {
        latent_rnn_fb<<<256, 256, 0, stream>>>(u, rn, inn, Winp, Wrec, states);
        out_proj<<<1024, 256, 0, stream>>>(states, Wout, outputs);
    }
}

// Round 23
// 584.424 us; speedup vs baseline: 1.6997x; 1.2771x over previous
//
#include <hip/hip_runtime.h>

#define NN 64
#define NI 6
#define TT 1024
#define BB 1024
#define TB (TT * BB)
#define NSCALE 0.13416407864998738f        // sqrt(2/alpha) * sigma
#define ARNSCALE 0.013416407864998739f     // alpha * NSCALE
#define RREC 72                            // rnu record: 64 rn' (-> x) + 6 uterm + 2 pad(0)
#define BSTRIDE (TT * RREC)                // 73728 floats per batch

typedef __attribute__((ext_vector_type(2))) unsigned int u32x2;

__device__ __forceinline__ float rdlane(float v, int l) {
    return __int_as_float(__builtin_amdgcn_readlane(__float_as_int(v), l));
}

// ---------------- Pass 1: build rnu[b][t][72] in d_ws ----------------
// record[0..63]  = ARNSCALE * rn[n][t][b]   (transposed, n contiguous)
// record[64..69] = u[i][t][b] + NSCALE*inn[i][t][b];  [70..71] = 0
__global__ __launch_bounds__(256) void build_rnu(
    const float* __restrict__ u,
    const float* __restrict__ rn,
    const float* __restrict__ inn,
    float* __restrict__ rnu)
{
    const int blk = blockIdx.x;
    const int t   = blk >> 4;
    const int b0  = (blk & 15) * 64;
    const int tid = threadIdx.x;

    __shared__ float lds[64][65];

    {   const int c  = tid & 63;
        const int r0 = tid >> 6;
#pragma unroll
        for (int it = 0; it < 16; ++it) {
            const int n = 4 * it + r0;
            lds[c][n] = ARNSCALE * rn[n * TB + t * BB + b0 + c];
        }
    }
    __syncthreads();
    {   const int cn = tid & 63;
        const int r0 = tid >> 6;
#pragma unroll
        for (int it = 0; it < 16; ++it) {
            const int r = 4 * it + r0;
            rnu[(b0 + r) * BSTRIDE + t * RREC + cn] = lds[r][cn];
        }
    }
    {   const int i  = tid & 7;
        const int br = tid >> 3;
#pragma unroll
        for (int it = 0; it < 2; ++it) {
            const int b = br + 32 * it;
            float v = 0.0f;
            if (i < NI) {
                const int g = i * TB + t * BB + b0 + b;
                v = fmaf(NSCALE, inn[g], u[g]);
            }
            rnu[(b0 + b) * BSTRIDE + t * RREC + 64 + i] = v;
        }
    }
}

// ---------------- Pass 2: recurrence, store-batched (vmcnt de-serialized) ----------------
// 1024 blocks x 64 thr (4 waves/CU). lane = neuron, block = batch. r19 step body
// (half-split 8x ds_read_b128, permlane32 exchange, readlane uterm, pinned weights)
// BUT the per-step global store is removed from the loop: lane keeps its own x in a
// 16-deep REGISTER history (static idx via fully-unrolled 16-step chunk; broadcast
// goes through a [2][16][64] LDS ring) and 16 coalesced stores are issued per chunk.
// Rationale: vmcnt retires in issue order, so a per-step store forces every
// prefetch-consume wait to drain that store to L2/HBM (~500cyc) -> r19's hidden wall.
__global__ __launch_bounds__(64, 1) void latent_rnn_sb(
    const float* __restrict__ rn_in,  // (B, T, 72) — reads
    float* __restrict__ x_out,        // (B, T, 72) — x writeback (same buffer)
    const float* __restrict__ Winp,   // (64, 6)
    const float* __restrict__ Wrec)   // (64, 64)
{
    const int hw = blockIdx.x;
    const int b  = (hw & 7) * 128 + (hw >> 3);   // XCD swizzle: 128 batches/XCD
    const int n  = threadIdx.x;
    const int h  = n >> 5;                       // half of x this lane reads
    const int hb = 32 * h;
    const int np = n ^ 32;

    __shared__ __align__(16) float xh_lds[2][16][64];   // broadcast ring, 8 KB

    // ---- permuted weight distribution (r17 scheme) ----
    float ws[32], wp[32];
#pragma unroll
    for (int j = 0; j < 32; j += 4) {
        const float4 a = *reinterpret_cast<const float4*>(Wrec + n  * NN + hb + j);
        const float4 c = *reinterpret_cast<const float4*>(Wrec + np * NN + hb + j);
        ws[j] = a.x; ws[j+1] = a.y; ws[j+2] = a.z; ws[j+3] = a.w;
        wp[j] = c.x; wp[j+1] = c.y; wp[j+2] = c.z; wp[j+3] = c.w;
    }
    float wi[NI];
#pragma unroll
    for (int i = 0; i < NI; ++i) wi[i] = Winp[n * NI + i];
#pragma unroll
    for (int k = 0; k < 32; ++k) { asm volatile("" : "+v"(ws[k])); asm volatile("" : "+v"(wp[k])); }

    // ---- probe permlane32_swap component convention ----
    bool useX;
    {
        u32x2 pb = __builtin_amdgcn_permlane32_swap((unsigned)n, (unsigned)n, false, false);
        useX = (pb.x == (unsigned)np);
    }

    const float* rptr = rn_in + b * BSTRIDE + n;             // rn' lane view
    const float* uptr = rn_in + b * BSTRIDE + 64 + (n & 7);  // uterm lane view
    float*       xdst = x_out + b * BSTRIDE + n;             // x writeback view

    // ---- init: the row read by step 0 (parity 1, row 15) = x[0] = 0 ----
    xh_lds[1][15][n] = 0.0f;

    // prefetch rings (depth 4, static slots): rnb/utb hold step t's rn'/uterm
    float rnb[4], utb[4];
#pragma unroll
    for (int d = 0; d < 4; ++d) {
        rnb[d] = rptr[d * RREC];
        utb[d] = uptr[d * RREC];
    }

    float xreg = 0.0f;
    float xh[16];   // register history (lane's own x), static indices only

#define STEP(tcur, slot, J, RDROW, WRROW, TPEXPR)                             \
    do {                                                                      \
        const float rcur = rnb[slot];                                         \
        const float ucur = utb[slot];                                         \
        { const int tp = (TPEXPR);                                            \
          rnb[slot] = rptr[tp * RREC];                                        \
          utb[slot] = uptr[tp * RREC]; }                                      \
        float a0 = rdlane(ucur, 0) * wi[0];                                   \
        float a1 = rdlane(ucur, 1) * wi[1];                                   \
        a0 = fmaf(rdlane(ucur, 2), wi[2], a0);                                \
        a1 = fmaf(rdlane(ucur, 3), wi[3], a1);                                \
        a0 = fmaf(rdlane(ucur, 4), wi[4], a0);                                \
        a1 = fmaf(rdlane(ucur, 5), wi[5], a1);                                \
        const float4* xrow = reinterpret_cast<const float4*>((RDROW) + hb);   \
        float c0 = 0.f, c1 = 0.f;                                             \
        _Pragma("unroll")                                                     \
        for (int q = 0; q < 8; ++q) {                                         \
            const float4 v = xrow[q];                                         \
            a0 = fmaf(v.x, ws[4*q+0], a0); c0 = fmaf(v.x, wp[4*q+0], c0);     \
            a1 = fmaf(v.y, ws[4*q+1], a1); c1 = fmaf(v.y, wp[4*q+1], c1);     \
            a0 = fmaf(v.z, ws[4*q+2], a0); c0 = fmaf(v.z, wp[4*q+2], c0);     \
            a1 = fmaf(v.w, ws[4*q+3], a1); c1 = fmaf(v.w, wp[4*q+3], c1);     \
        }                                                                     \
        const float p2 = c0 + c1;                                             \
        u32x2 sw = __builtin_amdgcn_permlane32_swap(                          \
            __float_as_uint(p2), __float_as_uint(p2), false, false);          \
        const float pr = __uint_as_float(useX ? sw.x : sw.y);                 \
        const float pre = (a0 + a1) + pr;                                     \
        const float xn  = fmaf(0.9f, xreg,                                    \
                               fmaf(0.1f, fmaxf(pre, 0.f), rcur));            \
        xreg = xn;                                                            \
        (WRROW)[n] = xn;       /* broadcast copy for step t+1 */              \
        xh[J] = xn;            /* register history for the batched flush */   \
    } while (0)

    // ---- 63 full chunks of 16 steps (t = 0 .. 1007); no clamps needed ----
#pragma unroll 1
    for (int c = 0; c < 63; ++c) {
        const int t0 = c << 4;
        float*       WR = &xh_lds[c & 1][0][0];
        const float* R0 = &xh_lds[(c + 1) & 1][15][0];
        STEP(t0 +  0, 0,  0, R0,          WR +  0*64, t0 +  4);
        STEP(t0 +  1, 1,  1, WR +  0*64,  WR +  1*64, t0 +  5);
        STEP(t0 +  2, 2,  2, WR +  1*64,  WR +  2*64, t0 +  6);
        STEP(t0 +  3, 3,  3, WR +  2*64,  WR +  3*64, t0 +  7);
        STEP(t0 +  4, 0,  4, WR +  3*64,  WR +  4*64, t0 +  8);
        STEP(t0 +  5, 1,  5, WR +  4*64,  WR +  5*64, t0 +  9);
        STEP(t0 +  6, 2,  6, WR +  5*64,  WR +  6*64, t0 + 10);
        STEP(t0 +  7, 3,  7, WR +  6*64,  WR +  7*64, t0 + 11);
        STEP(t0 +  8, 0,  8, WR +  7*64,  WR +  8*64, t0 + 12);
        STEP(t0 +  9, 1,  9, WR +  8*64,  WR +  9*64, t0 + 13);
        STEP(t0 + 10, 2, 10, WR +  9*64,  WR + 10*64, t0 + 14);
        STEP(t0 + 11, 3, 11, WR + 10*64,  WR + 11*64, t0 + 15);
        STEP(t0 + 12, 0, 12, WR + 11*64,  WR + 12*64, t0 + 16);
        STEP(t0 + 13, 1, 13, WR + 12*64,  WR + 13*64, t0 + 17);
        STEP(t0 + 14, 2, 14, WR + 13*64,  WR + 14*64, t0 + 18);
        STEP(t0 + 15, 3, 15, WR + 14*64,  WR + 15*64, t0 + 19);
        // batched flush: 16 coalesced stores, off the per-step critical path
#pragma unroll
        for (int jj = 0; jj < 16; ++jj)
            xdst[(t0 + jj) * RREC] = xh[jj];
    }

    // ---- tail chunk (c = 63, t = 1008 .. 1022, 15 steps; clamp prefetch) ----
    {
        float*       WR = &xh_lds[1][0][0];
        const float* R0 = &xh_lds[0][15][0];
#define TCL(tc) (((tc) + 4 < TT - 1) ? (tc) + 4 : TT - 1)
        STEP(1008, 0,  0, R0,          WR +  0*64, TCL(1008));
        STEP(1009, 1,  1, WR +  0*64,  WR +  1*64, TCL(1009));
        STEP(1010, 2,  2, WR +  1*64,  WR +  2*64, TCL(1010));
        STEP(1011, 3,  3, WR +  2*64,  WR +  3*64, TCL(1011));
        STEP(1012, 0,  4, WR +  3*64,  WR +  4*64, TCL(1012));
        STEP(1013, 1,  5, WR +  4*64,  WR +  5*64, TCL(1013));
        STEP(1014, 2,  6, WR +  5*64,  WR +  6*64, TCL(1014));
        STEP(1015, 3,  7, WR +  6*64,  WR +  7*64, TCL(1015));
        STEP(1016, 0,  8, WR +  7*64,  WR +  8*64, TCL(1016));
        STEP(1017, 1,  9, WR +  8*64,  WR +  9*64, TCL(1017));
        STEP(1018, 2, 10, WR +  9*64,  WR + 10*64, TCL(1018));
        STEP(1019, 3, 11, WR + 10*64,  WR + 11*64, TCL(1019));
        STEP(1020, 0, 12, WR + 11*64,  WR + 12*64, TCL(1020));
        STEP(1021, 1, 13, WR + 12*64,  WR + 13*64, TCL(1021));
        STEP(1022, 2, 14, WR + 13*64,  WR + 14*64, TCL(1022));
#undef TCL
#pragma unroll
        for (int jj = 0; jj < 15; ++jj)
            xdst[(1008 + jj) * RREC] = xh[jj];
    }
#undef STEP
}

// ---------------- Pass 3: transpose + fused output projection ----------------
// states[n][t][b] = (t==0) ? 0 : rnu[b][t-1][n];  outputs = states @ Wout^T.
__global__ __launch_bounds__(256) void trans_out(
    const float* __restrict__ rnu,
    const float* __restrict__ Wout,     // (2, 64)
    float* __restrict__ states,         // (64, T, B)
    float* __restrict__ outputs)        // (2, T, B)
{
    const int blk = blockIdx.x;
    const int t   = blk >> 4;
    const int b0  = (blk & 15) * 64;
    const int tid = threadIdx.x;

    __shared__ float xt[64][65];   // [b][n]
    __shared__ float wo[2][64];

    if (tid < 128) wo[tid >> 6][tid & 63] = Wout[tid];

    const int col = tid & 63;
    const int r0  = tid >> 6;
    if (t == 0) {
#pragma unroll
        for (int it = 0; it < 16; ++it) xt[4 * it + r0][col] = 0.0f;
    } else {
#pragma unroll
        for (int it = 0; it < 16; ++it) {
            const int r = 4 * it + r0;
            xt[r][col] = rnu[(b0 + r) * BSTRIDE + (t - 1) * RREC + col];
        }
    }
    __syncthreads();

#pragma unroll
    for (int it = 0; it < 16; ++it) {
        const int n = 4 * it + r0;
        states[n * TB + t * BB + b0 + col] = xt[col][n];
    }

    if (tid < 128) {
        const int o  = tid >> 6;
        const int bb = tid & 63;
        float acc = 0.0f;
#pragma unroll
        for (int k = 0; k < NN; ++k) acc = fmaf(xt[bb][k], wo[o][k], acc);
        outputs[o * TB + t * BB + b0 + bb] = acc;
    }
}

// ---------------- Fallback (no-workspace path, proven correct) ----------------
#define BARRIER() do {                                                        \
    __builtin_amdgcn_sched_barrier(0);                                        \
    asm volatile("s_waitcnt lgkmcnt(0)\n\ts_barrier" ::: "memory");           \
    __builtin_amdgcn_sched_barrier(0);                                        \
} while (0)

__global__ __launch_bounds__(256, 1) void latent_rnn_fb(
    const float* __restrict__ u, const float* __restrict__ rn,
    const float* __restrict__ inn, const float* __restrict__ Winp,
    const float* __restrict__ Wrec, float* __restrict__ states)
{
    const int hw  = blockIdx.x;
    const int lb  = (hw & 7) * 32 + (hw >> 3);
    const int b0  = lb * 4;
    const int tid = threadIdx.x;
    const int l   = tid & 63;
    const int w   = tid >> 6;
    const int n   = tid >> 2;
    const int bs  = tid & 3;

    __shared__ float rnT[2][NN][5];
    __shared__ float xT[2][NN][5];
    __shared__ float iT[2][4][8];

    float wreg[NN];
#pragma unroll
    for (int k = 0; k < NN; k += 4) {
        const float4 w4 = *reinterpret_cast<const float4*>(Wrec + l * NN + k);
        wreg[k] = w4.x; wreg[k+1] = w4.y; wreg[k+2] = w4.z; wreg[k+3] = w4.w;
    }
    float wi[NI];
#pragma unroll
    for (int i = 0; i < NI; ++i) wi[i] = Winp[l * NI + i];

    const float* rsrc = rn + n * TB + b0 + bs;
    float*       sdst = states + n * TB + b0 + bs;
    const bool  ist  = (tid < NI * 4);
    const int   ii   = tid >> 2;
    const int   ib   = tid & 3;
    const float* usrc = u   + ii * TB + b0 + ib;
    const float* isrc = inn + ii * TB + b0 + ib;

    rnT[0][n][bs] = rsrc[0];
    if (ist) iT[0][ib][ii] = fmaf(NSCALE, isrc[0], usrc[0]);
    xT[0][l][w] = 0.0f;

    float rnPF[4], uPF[4], iPF[4];
#pragma unroll
    for (int dd = 0; dd < 4; ++dd) {
        rnPF[dd] = rsrc[(dd + 1) * BB];
        if (ist) { uPF[dd] = usrc[(dd + 1) * BB]; iPF[dd] = isrc[(dd + 1) * BB]; }
    }
    __syncthreads();

    float xreg = 0.0f;

#define FSTEP(tcur, slot, CC)                                                 \
  {                                                                           \
    sdst[(tcur) * BB] = xT[CC][n][bs];                                        \
    const float rcur = rnT[CC][l][w];                                         \
    const float4 iv0 = *reinterpret_cast<const float4*>(&iT[CC][w][0]);       \
    const float2 iv1 = *reinterpret_cast<const float2*>(&iT[CC][w][4]);       \
    float a0 = 0.f, a1 = 0.f, a2 = 0.f, a3 = 0.f;                             \
    _Pragma("unroll")                                                         \
    for (int k = 0; k < NN; k += 4) {                                         \
        a0 = fmaf(rdlane(xreg, k + 0), wreg[k + 0], a0);                      \
        a1 = fmaf(rdlane(xreg, k + 1), wreg[k + 1], a1);                      \
        a2 = fmaf(rdlane(xreg, k + 2), wreg[k + 2], a2);                      \
        a3 = fmaf(rdlane(xreg, k + 3), wreg[k + 3], a3);                      \
    }                                                                         \
    a0 = fmaf(iv0.x, wi[0], a0); a1 = fmaf(iv0.y, wi[1], a1);                 \
    a2 = fmaf(iv0.z, wi[2], a2); a3 = fmaf(iv0.w, wi[3], a3);                 \
    a0 = fmaf(iv1.x, wi[4], a0); a1 = fmaf(iv1.y, wi[5], a1);                 \
    const float pre = (a0 + a1) + (a2 + a3);                                  \
    const float xn  = fmaf(0.9f, xreg,                                        \
                           fmaf(0.1f, fmaxf(pre, 0.f), ARNSCALE * rcur));     \
    xreg = xn;                                                                \
    xT[(CC) ^ 1][l][w] = xn;                                                  \
    rnT[(CC) ^ 1][n][bs] = rnPF[slot];                                        \
    if (ist) iT[(CC) ^ 1][ib][ii] = fmaf(NSCALE, iPF[slot], uPF[slot]);       \
    { int tp = (tcur) + 5; if (tp > TT - 2) tp = TT - 2;                      \
      rnPF[slot] = rsrc[tp * BB];                                             \
      if (ist) { uPF[slot] = usrc[tp * BB]; iPF[slot] = isrc[tp * BB]; } }    \
    BARRIER();                                                                \
  }

#pragma unroll 1
    for (int t = 0; t < 1020; t += 4) {
        FSTEP(t + 0, 0, 0);
        FSTEP(t + 1, 1, 1);
        FSTEP(t + 2, 2, 0);
        FSTEP(t + 3, 3, 1);
    }
    FSTEP(1020, 0, 0);
    FSTEP(1021, 1, 1);
    FSTEP(1022, 2, 0);
#undef FSTEP

    sdst[(TT - 1) * BB] = xT[1][n][bs];
}

__global__ __launch_bounds__(256) void out_proj(
    const float* __restrict__ states,
    const float* __restrict__ Wout,
    float* __restrict__ outputs)
{
    const int g4 = (blockIdx.x * 256 + threadIdx.x) * 4;
    float4 a0 = {0.f, 0.f, 0.f, 0.f};
    float4 a1 = {0.f, 0.f, 0.f, 0.f};
#pragma unroll
    for (int k = 0; k < NN; ++k) {
        const float4 s = *reinterpret_cast<const float4*>(states + k * TB + g4);
        const float w0 = Wout[k];
        const float w1 = Wout[NN + k];
        a0.x = fmaf(s.x, w0, a0.x); a0.y = fmaf(s.y, w0, a0.y);
        a0.z = fmaf(s.z, w0, a0.z); a0.w = fmaf(s.w, w0, a0.w);
        a1.x = fmaf(s.x, w1, a1.x); a1.y = fmaf(s.y, w1, a1.y);
        a1.z = fmaf(s.z, w1, a1.z); a1.w = fmaf(s.w, w1, a1.w);
    }
    *reinterpret_cast<float4*>(outputs + g4)      = a0;
    *reinterpret_cast<float4*>(outputs + TB + g4) = a1;
}

extern "C" void kernel_launch(void* const* d_in, const int* in_sizes, int n_in,
                              void* d_out, int out_size, void* d_ws, size_t ws_size,
                              hipStream_t stream) {
    const float* u    = (const float*)d_in[0];
    const float* rn   = (const float*)d_in[1];
    const float* inn  = (const float*)d_in[2];
    const float* Winp = (const float*)d_in[3];
    const float* Wrec = (const float*)d_in[4];
    const float* Wout = (const float*)d_in[5];

    float* states  = (float*)d_out;                          // 64*1024*1024
    float* outputs = (float*)d_out + (size_t)NN * TT * BB;   // 2*1024*1024

    const size_t need = (size_t)BB * TT * RREC * sizeof(float);  // ~302 MB
    if (ws_size >= need) {
        float* rnu = (float*)d_ws;
        build_rnu<<<TT * 16, 256, 0, stream>>>(u, rn, inn, rnu);
        latent_rnn_sb<<<1024, 64, 0, stream>>>(rnu, rnu, Winp, Wrec);
        trans_out<<<TT * 16, 256, 0, stream>>>(rnu, Wout, states, outputs);
    } else {
        latent_rnn_fb<<<256, 256, 0, stream>>>(u, rn, inn, Winp, Wrec, states);
        out_proj<<<1024, 256, 0, stream>>>(states, Wout, outputs);
    }
}